// Round 5
// baseline (8979.663 us; speedup 1.0000x reference)
//
#include <hip/hip_runtime.h>
#include <hip/hip_bf16.h>

typedef __attribute__((ext_vector_type(8))) short bf16x8;
typedef __attribute__((ext_vector_type(4))) float f32x4;
typedef __attribute__((ext_vector_type(4))) unsigned int u32x4;

#define MFMA16(a,b,c) __builtin_amdgcn_mfma_f32_16x16x32_bf16((a),(b),(c),0,0,0)

// coherent (agent-scope, L2-bypass) asm memory ops — WRITE path only.
// Reads are normal cached loads; coherence comes from the per-barrier L2/L1 invalidate.
#define GLOADD(dst, ptr) asm volatile("global_load_dword %0, %1, off sc1"   : "=v"(dst) : "v"(ptr))
#define GSTORE4(ptr, v)  asm volatile("global_store_dwordx4 %0, %1, off sc1" :: "v"(ptr), "v"(v) : "memory")
#define GSTORED(ptr, v)  asm volatile("global_store_dword %0, %1, off sc1"   :: "v"(ptr), "v"(v) : "memory")
#define VMWAIT0 do { asm volatile("s_waitcnt vmcnt(0)" ::: "memory"); __builtin_amdgcn_sched_barrier(0); } while(0)

// ---------------- workspace layout (byte offsets) ----------------
static constexpr long OFF_WT  = 0;           // bf16 transposed weights, 46,137,344 B
static constexpr long OFF_H16 = 46137344;    // h bf16 [2 parity][4 unit][64][1024] = 1,048,576 B
static constexpr long OFF_BAR = 48234496;    // flags[256]@64B stride (16 KiB) + barGenA[8]@64B
// end < 48 MiB

// element offsets (bf16) within weight region
static constexpr long E_FW_WXT0 = 0;         // [3072][512]
static constexpr long E_FW_WHT0 = 1572864;   // [3072][1024]
static constexpr long E_FW_WXT1 = 4718592;
static constexpr long E_FW_WHT1 = 7864320;
static constexpr long E_BW_WXT0 = 11010048;
static constexpr long E_BW_WHT0 = 12582912;
static constexpr long E_BW_WXT1 = 15728640;
static constexpr long E_BW_WHT1 = 18874368;
static constexpr long E_FCWT    = 22020096;  // [512][2048]

static constexpr long OUT_FWH = 16777216;    // fw_h [2][64][1024] in d_out (float offsets)
static constexpr long OUT_BWH = 16908288;

__device__ __forceinline__ float sig_(float x) {
  x = fminf(fmaxf(x, -30.f), 30.f);
  return 1.f / (1.f + __expf(-x));
}
__device__ __forceinline__ float tanh_(float x) {
  x = fminf(fmaxf(x, -15.f), 15.f);
  float e = __expf(2.f * x);
  return (e - 1.f) / (e + 1.f);
}
__device__ __forceinline__ bf16x8 bc8(uint4 v) { return __builtin_bit_cast(bf16x8, v); }
__device__ __forceinline__ bf16x8 bc8(u32x4 v) { return __builtin_bit_cast(bf16x8, v); }
__device__ __forceinline__ unsigned f2bfu(float f) {
  __hip_bfloat16 h = __float2bfloat16(f);
  return (unsigned)*(unsigned short*)&h;
}
// 8 fp32 (two uint4-of-float4) -> 8 packed bf16 (one uint4)
__device__ __forceinline__ uint4 cvt8v(uint4 u0, uint4 u1) {
  float4 a = __builtin_bit_cast(float4, u0);
  float4 b = __builtin_bit_cast(float4, u1);
  uint4 r;
  r.x = f2bfu(a.x) | (f2bfu(a.y) << 16);
  r.y = f2bfu(a.z) | (f2bfu(a.w) << 16);
  r.z = f2bfu(b.x) | (f2bfu(b.y) << 16);
  r.w = f2bfu(b.z) | (f2bfu(b.w) << 16);
  return r;
}

// ---------------- transpose+cast: src f32 [R][C] -> dst bf16 [C][R] ----------------
__global__ void transpose_cast(const float* __restrict__ src, __hip_bfloat16* __restrict__ dst,
                               int R, int C) {
  __shared__ float tile[32][33];
  int tx = threadIdx.x, ty = threadIdx.y;
  int c0 = blockIdx.x * 32, r0 = blockIdx.y * 32;
#pragma unroll
  for (int i = 0; i < 32; i += 8) tile[ty + i][tx] = src[(long)(r0 + ty + i) * C + c0 + tx];
  __syncthreads();
#pragma unroll
  for (int i = 0; i < 32; i += 8)
    dst[(long)(c0 + ty + i) * R + r0 + tx] = __float2bfloat16(tile[tx][ty + i]);
}

// ---------------- persistent fused BiGRU ----------------
// 256 blocks x 512 threads (8 waves), 1 block/CU.
// waves 0-3: K-half 0 (batch quarters 0-3); waves 4-7: K-half 1; LDS reduce of partials.
// blocks   0.. 63: unit0 fw L0 (blocks  0..31 also FC fw)
// blocks  64..127: unit1 bw L0 (blocks 64..95 also FC bw)
// blocks 128..191: unit2 fw L1;  192..255: unit3 bw L1
// Coherence protocol: ALL global stores are sc1 (write-through; L2 never dirty).
// Cross-block reads are normal cached loads; at every device barrier one wave/CU issues
// an agent-acquire fence (buffer_inv: L1+XCD-L2 flash invalidate) => no cache line
// survives a barrier, so cached reads always see the L3-coherent data.
__global__ __launch_bounds__(512, 1)
void bigru_persist(char* __restrict__ ws, const float* __restrict__ xf,
                   const float* __restrict__ fwbx0, const float* __restrict__ fwbh0,
                   const float* __restrict__ fwbx1, const float* __restrict__ fwbh1,
                   const float* __restrict__ bwbx0, const float* __restrict__ bwbh0,
                   const float* __restrict__ bwbx1, const float* __restrict__ bwbh1,
                   const float* __restrict__ fcb, float* __restrict__ dout) {
  extern __shared__ uint4 wlds[];            // 131072 B = 128 weight frags * 64 lanes * 16B
  __shared__ float redu[4 * 64 * 17];        // cross-K-half reduce, +17 pad (17408 B)
  __shared__ unsigned short stg[64 * 16];    // h store staging (2048 B)

  char* h16b = ws + OFF_H16;
  const __hip_bfloat16* wt = (const __hip_bfloat16*)(ws + OFF_WT);
  unsigned* flags   = (unsigned*)(ws + OFF_BAR);            // [blk] stride 16 uints
  unsigned* barGenA = (unsigned*)(ws + OFF_BAR + 16384);    // 8 replicated gen lines

  const int tid  = threadIdx.x;
  const int lane = tid & 63;
  const int wid  = tid >> 6;      // 0..7
  const int wsub = wid & 3;       // batch quarter (rows wsub*16+rr)
  const int khalf = wid >> 2;     // K half
  const int rr = lane & 15, qq = lane >> 4;
  const int blk = blockIdx.x;
  const int unit = blk >> 6;
  const int j0 = (blk & 63) << 4;
  const bool isL1 = unit >= 2;
  const bool hasFC = (!isL1) && ((blk & 63) < 32);
  const int fcDir = unit;         // valid when hasFC
  const int j0f = (blk & 31) << 4;

  long eWh, eWx; int ldx; const float *bx, *bh; long dhOff;
  switch (unit) {
    case 0:  eWh = E_FW_WHT0; eWx = E_FW_WXT0; ldx = 512;  bx = fwbx0; bh = fwbh0; dhOff = OUT_FWH;         break;
    case 1:  eWh = E_BW_WHT0; eWx = E_BW_WXT0; ldx = 512;  bx = bwbx0; bh = bwbh0; dhOff = OUT_BWH;         break;
    case 2:  eWh = E_FW_WHT1; eWx = E_FW_WXT1; ldx = 1024; bx = fwbx1; bh = fwbh1; dhOff = OUT_FWH + 65536; break;
    default: eWh = E_BW_WHT1; eWx = E_BW_WXT1; ldx = 1024; bx = bwbx1; bh = bwbh1; dhOff = OUT_BWH + 65536; break;
  }

  // ---- one-time LDS weight staging (128 frags: Wh r/z/n = 0..95, Wx-r(+z for L0) = 96..127) ----
  for (int f = wid; f < 128; f += 8) {
    const __hip_bfloat16* src;
    if (f < 96) {
      int g = f >> 5, kt = f & 31;                       // Wh gates r,z,n ; K=1024
      src = wt + eWh + (long)(g * 1024 + j0 + rr) * 1024 + kt * 32 + qq * 8;
    } else if (isL1) {
      int kt = f - 96;                                   // Wx-r ; K=1024
      src = wt + eWx + (long)(j0 + rr) * (long)ldx + kt * 32 + qq * 8;
    } else {
      int fx = f - 96, g = fx >> 4, kt = fx & 15;        // Wx-r (g=0), Wx-z (g=1) ; K=512
      src = wt + eWx + (long)(g * 1024 + j0 + rr) * (long)ldx + kt * 32 + qq * 8;
    }
    wlds[f * 64 + lane] = *(const uint4*)src;
  }

  // ---- register weights (per-thread K-half slice only => no spills) ----
  // L1: wreg[0..15] = Wx-n half. L0: wreg[0..7] = Wx-n half; wreg[8..23] = FC half.
  uint4 wreg[24];
  if (isL1) {
#pragma unroll
    for (int k = 0; k < 16; ++k)
      wreg[k] = *(const uint4*)(wt + eWx + (long)(2048 + j0 + rr) * 1024 + (khalf * 16 + k) * 32 + qq * 8);
  } else {
#pragma unroll
    for (int k = 0; k < 8; ++k)
      wreg[k] = *(const uint4*)(wt + eWx + (long)(2048 + j0 + rr) * 512 + (khalf * 8 + k) * 32 + qq * 8);
    if (hasFC) {
#pragma unroll
      for (int k = 0; k < 16; ++k)
        wreg[8 + k] = *(const uint4*)(wt + E_FCWT + (long)(j0f + rr) * 2048 + fcDir * 1024 + (khalf * 16 + k) * 32 + qq * 8);
    }
  }
  // L1 Wx-z slice: per-step cached loads (read-only weights, refetched from L3 after inv)
  const char* wzb = (const char*)(wt + eWx + (long)(1024 + j0 + rr) * 1024) + khalf * 1024 + qq * 16;

  // ---- hoisted per-lane constants ----
  const int j = j0 + rr;
  const float bxr = bx[j], bxz = bx[1024 + j], bxn = bx[2048 + j];
  const float bhr = bh[j], bhz = bh[1024 + j], bhn = bh[2048 + j];
  const float bvFC = hasFC ? fcb[j0f + rr] : 0.f;

  float hreg[4] = {0.f, 0.f, 0.f, 0.f};   // fp32 master h (kept by waves 0-3)
  const int lastS = isL1 ? 512 : 511;

  __syncthreads();

  for (int s = 0; s <= 513; ++s) {
    // ---------------- GRU ----------------
    bool act; int rp, t;
    if (!isL1) { act = (s <= 511);           rp = s & 1;       t = (unit == 0) ? s : 511 - s; }
    else       { act = (s >= 1 && s <= 512); rp = (s - 1) & 1; t = (unit == 2) ? s - 1 : 512 - s; }
    if (act) {
      const int wp = rp ^ 1;
      f32x4 aR = {0.f,0.f,0.f,0.f}, aZ = {0.f,0.f,0.f,0.f};
      f32x4 aNH = {0.f,0.f,0.f,0.f}, aNX = {0.f,0.f,0.f,0.f};

      { // ---- h-part: 16 frags per wave (this wave's K-half), cached loads (L2-served) ----
        const char* pAh = h16b + (long)rp * 524288 + unit * 131072 + (wsub * 16 + rr) * 2048 + khalf * 1024 + qq * 16;
        uint4 A[16];
#pragma unroll
        for (int i = 0; i < 16; ++i) A[i] = *(const uint4*)(pAh + i * 64);
#pragma unroll
        for (int i = 0; i < 16; ++i) {
          const int kt = khalf * 16 + i;
          bf16x8 a = bc8(A[i]);
          aR  = MFMA16(a, bc8(wlds[kt * 64 + lane]), aR);
          aZ  = MFMA16(a, bc8(wlds[(32 + kt) * 64 + lane]), aZ);
          aNH = MFMA16(a, bc8(wlds[(64 + kt) * 64 + lane]), aNH);
        }
      }

      if (!isL1) {
        // ---- x-part: read-only fp32 x, cached loads + cvt ----
        const char* pAx = (const char*)xf + (long)(wsub * 16 + rr) * 1048576 + (long)t * 2048 + khalf * 1024 + qq * 32;
#pragma unroll
        for (int i = 0; i < 8; ++i) {
          uint4 u0 = *(const uint4*)(pAx + i * 128);
          uint4 u1 = *(const uint4*)(pAx + i * 128 + 16);
          const int ktg = khalf * 8 + i;
          bf16x8 a = bc8(cvt8v(u0, u1));
          aR  = MFMA16(a, bc8(wlds[(96 + ktg) * 64 + lane]), aR);
          aZ  = MFMA16(a, bc8(wlds[(112 + ktg) * 64 + lane]), aZ);
          aNX = MFMA16(a, bc8(wreg[i]), aNX);
        }
      } else {
        // ---- y-part: A = L0 output h16[s&1][unit-2], cached loads ----
        const char* pAy = h16b + (long)(s & 1) * 524288 + (unit - 2) * 131072 + (wsub * 16 + rr) * 2048 + khalf * 1024 + qq * 16;
        uint4 A[16];
#pragma unroll
        for (int i = 0; i < 16; ++i) A[i] = *(const uint4*)(pAy + i * 64);
#pragma unroll
        for (int i = 0; i < 16; ++i) {
          const int ktg = khalf * 16 + i;
          bf16x8 a = bc8(A[i]);
          uint4 wz = *(const uint4*)(wzb + i * 64);   // cached Wx-z
          aR  = MFMA16(a, bc8(wlds[(96 + ktg) * 64 + lane]), aR);
          aZ  = MFMA16(a, bc8(wz), aZ);
          aNX = MFMA16(a, bc8(wreg[i]), aNX);
        }
      }

      // ---- cross-K-half reduce + epilogue ----
      __syncthreads();
      if (khalf) {
        float* rb = &redu[(wsub * 64 + lane) * 17];
#pragma unroll
        for (int g = 0; g < 4; ++g) { rb[g] = aR[g]; rb[4 + g] = aZ[g]; rb[8 + g] = aNH[g]; rb[12 + g] = aNX[g]; }
      }
      __syncthreads();
      if (!khalf) {
        const float* rb = &redu[(wsub * 64 + lane) * 17];
#pragma unroll
        for (int g = 0; g < 4; ++g) {
          const int row = wsub * 16 + qq * 4 + g;
          const float r_ = sig_((aR[g] + rb[g]) + bxr + bhr);
          const float z_ = sig_((aZ[g] + rb[4 + g]) + bxz + bhz);
          const float n_ = tanh_((aNX[g] + rb[12 + g]) + bxn + r_ * ((aNH[g] + rb[8 + g]) + bhn));
          const float hn2 = (1.f - z_) * n_ + z_ * hreg[g];
          hreg[g] = hn2;
          const __hip_bfloat16 hb = __float2bfloat16(hn2);
          stg[row * 16 + rr] = *(const unsigned short*)&hb;
          if (s == lastS) GSTORED(dout + dhOff + (long)row * 1024 + j, hn2);  // sc1: L2 stays clean
        }
      }
      __syncthreads();
      // ---- wide coherent h store: 128 x 16B per block ----
      if (tid < 128) {
        const int row = tid >> 1, seg = tid & 1;
        u32x4 v = *(const u32x4*)&stg[row * 16 + seg * 8];
        char* pd = h16b + (long)wp * 524288 + unit * 131072 + row * 2048 + j0 * 2 + seg * 16;
        GSTORE4(pd, v);
      }
    }

    // ---------------- FC (reads h16[(s-1)&1][unit 2|3], cached) ----------------
    if (hasFC && s >= 2) {
      const int tf = fcDir ? (513 - s) : (s - 2);
      const char* pAf = h16b + (long)((s - 1) & 1) * 524288 + (2 + fcDir) * 131072 + (wsub * 16 + rr) * 2048 + khalf * 1024 + qq * 16;
      f32x4 fa = {0.f,0.f,0.f,0.f};
      uint4 F[16];
#pragma unroll
      for (int i = 0; i < 16; ++i) F[i] = *(const uint4*)(pAf + i * 64);
#pragma unroll
      for (int i = 0; i < 16; ++i) fa = MFMA16(bc8(F[i]), bc8(wreg[8 + i]), fa);
      __syncthreads();
      if (khalf) {
        float* rb = &redu[(wsub * 64 + lane) * 17];
#pragma unroll
        for (int g = 0; g < 4; ++g) rb[g] = fa[g];
      }
      __syncthreads();
      if (!khalf) {
        const float* rb = &redu[(wsub * 64 + lane) * 17];
        const int jf = j0f + rr;
        const bool first = fcDir ? (tf >= 256) : (tf <= 255);
        if (first) {
#pragma unroll
          for (int g = 0; g < 4; ++g) {
            const int b = wsub * 16 + qq * 4 + g;
            float v = (fa[g] + rb[g]) + bvFC;
            GSTORED(dout + (long)b * 262144 + (long)tf * 512 + jf, v);
          }
        } else {
          float pv[4];
#pragma unroll
          for (int g = 0; g < 4; ++g)
            GLOADD(pv[g], dout + (long)(wsub * 16 + qq * 4 + g) * 262144 + (long)tf * 512 + jf);
          VMWAIT0;
#pragma unroll
          for (int g = 0; g < 4; ++g) {
            float v = pv[g] + (fa[g] + rb[g]);
            GSTORED(dout + (long)(wsub * 16 + qq * 4 + g) * 262144 + (long)tf * 512 + jf, v);
          }
        }
      }
    }

    // ---------------- device barrier + cache-invalidate (the coherence point) ----------------
    if (s < 513) {
      asm volatile("s_waitcnt vmcnt(0)" ::: "memory");   // drain this wave's sc1 stores to L3
      __syncthreads();
      const unsigned gen = (unsigned)(s + 1);
      if (blk == 0) {
        if (tid == 0)
          __hip_atomic_store(flags, gen, __ATOMIC_RELAXED, __HIP_MEMORY_SCOPE_AGENT);
        if (tid < 256) {
          while (__hip_atomic_load(flags + tid * 16, __ATOMIC_RELAXED, __HIP_MEMORY_SCOPE_AGENT) < gen)
            __builtin_amdgcn_s_sleep(1);
        }
        __syncthreads();
        if (tid < 8)
          __hip_atomic_store(barGenA + tid * 16, gen, __ATOMIC_RELAXED, __HIP_MEMORY_SCOPE_AGENT);
      } else {
        if (tid == 0) {
          __hip_atomic_store(flags + blk * 16, gen, __ATOMIC_RELAXED, __HIP_MEMORY_SCOPE_AGENT);
          while (__hip_atomic_load(barGenA + (blk & 7) * 16, __ATOMIC_RELAXED, __HIP_MEMORY_SCOPE_AGENT) < gen)
            __builtin_amdgcn_s_sleep(1);
        }
      }
      __syncthreads();
      // one wave per CU invalidates L1 + XCD-L2 (L2 has no dirty lines: all stores were sc1)
      if (wid == 0) __builtin_amdgcn_fence(__ATOMIC_ACQUIRE, "agent");
      __syncthreads();
    }
  }
}

extern "C" void kernel_launch(void* const* d_in, const int* in_sizes, int n_in,
                              void* d_out, int out_size, void* d_ws, size_t ws_size,
                              hipStream_t stream) {
  (void)in_sizes; (void)n_in; (void)out_size; (void)ws_size;
  char* ws = (char*)d_ws;
  const float* x = (const float*)d_in[0];
  __hip_bfloat16* wt = (__hip_bfloat16*)(ws + OFF_WT);

  // zero h state + barrier flags (graph replays re-run these)
  (void)hipMemsetAsync(ws + OFF_H16, 0, 1048576, stream);
  (void)hipMemsetAsync(ws + OFF_BAR, 0, 16896, stream);

  // transpose-cast weights: src [K][3072] -> dst [3072][K] (and fc [2048][512] -> [512][2048])
  dim3 tb(32, 8);
  transpose_cast<<<dim3(96, 16), tb, 0, stream>>>((const float*)d_in[1],  wt + E_FW_WXT0, 512,  3072);
  transpose_cast<<<dim3(96, 32), tb, 0, stream>>>((const float*)d_in[2],  wt + E_FW_WHT0, 1024, 3072);
  transpose_cast<<<dim3(96, 32), tb, 0, stream>>>((const float*)d_in[5],  wt + E_FW_WXT1, 1024, 3072);
  transpose_cast<<<dim3(96, 32), tb, 0, stream>>>((const float*)d_in[6],  wt + E_FW_WHT1, 1024, 3072);
  transpose_cast<<<dim3(96, 16), tb, 0, stream>>>((const float*)d_in[9],  wt + E_BW_WXT0, 512,  3072);
  transpose_cast<<<dim3(96, 32), tb, 0, stream>>>((const float*)d_in[10], wt + E_BW_WHT0, 1024, 3072);
  transpose_cast<<<dim3(96, 32), tb, 0, stream>>>((const float*)d_in[13], wt + E_BW_WXT1, 1024, 3072);
  transpose_cast<<<dim3(96, 32), tb, 0, stream>>>((const float*)d_in[14], wt + E_BW_WHT1, 1024, 3072);
  transpose_cast<<<dim3(16, 64), tb, 0, stream>>>((const float*)d_in[17], wt + E_FCWT,    2048, 512);

  const float* fwbx0 = (const float*)d_in[3];
  const float* fwbh0 = (const float*)d_in[4];
  const float* fwbx1 = (const float*)d_in[7];
  const float* fwbh1 = (const float*)d_in[8];
  const float* bwbx0 = (const float*)d_in[11];
  const float* bwbh0 = (const float*)d_in[12];
  const float* bwbx1 = (const float*)d_in[15];
  const float* bwbh1 = (const float*)d_in[16];
  const float* fcb   = (const float*)d_in[18];
  float* dop = (float*)d_out;

  static bool attrSet = false;
  if (!attrSet) {
    (void)hipFuncSetAttribute(reinterpret_cast<const void*>(bigru_persist),
                              hipFuncAttributeMaxDynamicSharedMemorySize, 131072);
    attrSet = true;
  }

  void* args[] = {&ws, &x, &fwbx0, &fwbh0, &fwbx1, &fwbh1,
                  &bwbx0, &bwbh0, &bwbx1, &bwbh1, &fcb, &dop};
  hipError_t e = hipLaunchCooperativeKernel(reinterpret_cast<const void*>(bigru_persist),
                                            dim3(256), dim3(512), args, 131072, stream);
  if (e != hipSuccess) {
    // fallback: plain launch (256 blocks on 256 CUs, 1 block/CU -> co-resident in practice)
    bigru_persist<<<dim3(256), dim3(512), 131072, stream>>>(
        ws, (const float*)x, fwbx0, fwbh0, fwbx1, fwbh1,
        bwbx0, bwbh0, bwbx1, bwbh1, fcb, dop);
  }
}